// Round 2
// baseline (150.661 us; speedup 1.0000x reference)
//
#include <hip/hip_runtime.h>

// Problem constants (from reference): B=4, T=512, S=256, V=50257.
#define DIM_B 4
#define DIM_T 512
#define DIM_S 256
#define DIM_V 50257

// ---- Kernel 1: flat grid-stride zero of the whole output ----
// out_size = B*T*V = 102,926,336 floats, divisible by 4 -> clean float4 path,
// 16B-aligned base (device allocation). Grid-stride keeps the whole GPU's
// write front contiguous (fillBuffer-style DRAM page locality), unlike the
// previous per-block-row streams (2048 independent write fronts -> ~3.8 TB/s).
__global__ __launch_bounds__(256) void zero_out_kernel(float4* __restrict__ out, int n4) {
    const int stride = gridDim.x * blockDim.x;
    const float4 z = make_float4(0.0f, 0.0f, 0.0f, 0.0f);
    for (int i = blockIdx.x * blockDim.x + threadIdx.x; i < n4; i += stride) {
        out[i] = z;
    }
}

// ---- Kernel 2: scatter-add ----
// One thread per (b,t,s): out[b,t,src[b,s]] += p_pos[b,t,s].
// Row-exclusive per (b,t) except duplicates within the row -> atomicAdd.
// 524,288 atomics into 50257-wide rows: expected collisions ~0.65/row.
__global__ __launch_bounds__(256) void scatter_kernel(
    const float* __restrict__ p_pos,   // [B, T, S]
    const int*   __restrict__ src,     // [B, S] (int64 narrowed to int32)
    float*       __restrict__ out)     // [B, T, V]
{
    const int row = blockIdx.x;        // row = b*T + t, S == blockDim.x
    const int b   = row / DIM_T;
    const int tid = threadIdx.x;

    const int   v_idx = src[b * DIM_S + tid];
    const float val   = p_pos[(size_t)row * DIM_S + tid];
    atomicAdd(out + (size_t)row * DIM_V + v_idx, val);
}

extern "C" void kernel_launch(void* const* d_in, const int* in_sizes, int n_in,
                              void* d_out, int out_size, void* d_ws, size_t ws_size,
                              hipStream_t stream) {
    const float* p_pos = (const float*)d_in[0];   // [B,T,S]
    // d_in[1] = p_target_vocab — dead data (shape-only in the reference).
    const int*   src   = (const int*)d_in[2];     // [B,S]
    float*       out   = (float*)d_out;           // [B,T,V]

    const int n4 = out_size >> 2;                 // 25,731,584 float4s
    zero_out_kernel<<<2048, 256, 0, stream>>>((float4*)out, n4);
    scatter_kernel<<<DIM_B * DIM_T, DIM_S, 0, stream>>>(p_pos, src, out);
}